// Round 3
// baseline (1684.036 us; speedup 1.0000x reference)
//
#include <hip/hip_runtime.h>
#include <hip/hip_bf16.h>

#define Nn 3072
#define E_IN 98304
#define EP (E_IN + Nn)      // 101376 edges incl self loops
#define NNsq ((size_t)Nn * (size_t)Nn)

__device__ __forceinline__ float eluf(float a) { return a > 0.f ? a : (expf(a) - 1.f); }

// ---------- softmax of s1 rows + entropy partial ----------
__global__ __launch_bounds__(256) void k_softmax(const float* __restrict__ s1,
                                                 float* __restrict__ s_soft,
                                                 float* __restrict__ scal) {
    int n = blockIdx.x * 256 + threadIdx.x;   // 12*256 = 3072
    float v[16], mx = -1e30f;
#pragma unroll
    for (int i = 0; i < 16; i++) { v[i] = s1[n * 16 + i]; mx = fmaxf(mx, v[i]); }
    float s = 0.f;
#pragma unroll
    for (int i = 0; i < 16; i++) { v[i] = expf(v[i] - mx); s += v[i]; }
    float inv = 1.f / s, ent = 0.f;
#pragma unroll
    for (int i = 0; i < 16; i++) {
        float p = v[i] * inv;
        s_soft[n * 16 + i] = p;
        ent += p * logf(p + 1e-15f);
    }
    __shared__ float wsum[4];
    for (int off = 32; off; off >>= 1) ent += __shfl_xor(ent, off);
    if ((threadIdx.x & 63) == 0) wsum[threadIdx.x >> 6] = ent;
    __syncthreads();
    if (threadIdx.x == 0) atomicAdd(&scal[2], wsum[0] + wsum[1] + wsum[2] + wsum[3]);
}

// ---------- h1 = x @ w1  [3072,128]x[128,32] ----------
__global__ __launch_bounds__(256) void k_gemm1(const float* __restrict__ x,
                                               const float* __restrict__ w1,
                                               float* __restrict__ h1) {
    __shared__ float xs[8 * 128];
    int n0 = blockIdx.x * 8;
    for (int idx = threadIdx.x; idx < 1024; idx += 256) xs[idx] = x[(size_t)n0 * 128 + idx];
    __syncthreads();
    int r = threadIdx.x >> 5, j = threadIdx.x & 31;
    float acc = 0.f;
#pragma unroll 8
    for (int k = 0; k < 128; k++) acc += xs[r * 128 + k] * w1[k * 32 + j];
    h1[(n0 + r) * 32 + j] = acc;
}

// ---------- EGAT1 pass A: per-edge attention logits + denom ----------
__global__ __launch_bounds__(256) void k_e1a(const int* __restrict__ ei,
                                             const float* __restrict__ a1,
                                             const float* __restrict__ h1,
                                             float* __restrict__ ex1,
                                             float* __restrict__ denom1) {
    __shared__ float a1s[64];
    if (threadIdx.x < 64) a1s[threadIdx.x] = a1[threadIdx.x];
    __syncthreads();
    int e = blockIdx.x * 256 + threadIdx.x;
    if (e >= EP) return;
    int row = (e < E_IN) ? ei[e] : (e - E_IN);
    int col = (e < E_IN) ? ei[E_IN + e] : (e - E_IN);
    const float4* H = (const float4*)h1;
    float hr[32], hc[32];
#pragma unroll
    for (int k = 0; k < 8; k++) {
        float4 r4 = H[row * 8 + k], c4 = H[col * 8 + k];
        hr[k*4+0]=r4.x; hr[k*4+1]=r4.y; hr[k*4+2]=r4.z; hr[k*4+3]=r4.w;
        hc[k*4+0]=c4.x; hc[k*4+1]=c4.y; hc[k*4+2]=c4.z; hc[k*4+3]=c4.w;
    }
#pragma unroll
    for (int h = 0; h < 4; h++) {
        float t = 0.f;
#pragma unroll
        for (int d = 0; d < 8; d++)
            t += hr[h*8+d] * a1s[h*16+d] + hc[h*8+d] * a1s[h*16+8+d];
        t = t > 0.f ? t : 0.2f * t;
        float ex = expf(t);                 // softmax shift-invariant: skip segment-max
        ex1[e * 4 + h] = ex;
        atomicAdd(&denom1[row * 4 + h], ex);
    }
}

// ---------- EGAT1 pass B: normalize, write e1, scatter messages ----------
__global__ __launch_bounds__(256) void k_e1b(const int* __restrict__ ei,
                                             const float* __restrict__ ea,
                                             const float* __restrict__ h1,
                                             const float* __restrict__ ex1,
                                             const float* __restrict__ denom1,
                                             float* __restrict__ e1,
                                             float* __restrict__ hL1acc) {
    int id = blockIdx.x * 256 + threadIdx.x;   // 4*EP
    if (id >= 4 * EP) return;
    int e = id >> 2, h = id & 3;
    int row = (e < E_IN) ? ei[e] : (e - E_IN);
    int col = (e < E_IN) ? ei[E_IN + e] : (e - E_IN);
    float alpha = ex1[e * 4 + h] / (denom1[row * 4 + h] + 1e-16f);
    float eac[3];
#pragma unroll
    for (int c = 0; c < 3; c++) eac[c] = (e < E_IN) ? ea[(size_t)e * 3 + c] : 1.0f;
    const float4* H = (const float4*)h1;
    float4 q0 = H[col * 8 + h * 2], q1 = H[col * 8 + h * 2 + 1];
    float hcv[8] = {q0.x,q0.y,q0.z,q0.w,q1.x,q1.y,q1.z,q1.w};
#pragma unroll
    for (int c = 0; c < 3; c++) {
        float ac = alpha * eac[c];
        e1[(size_t)e * 12 + h * 3 + c] = ac;
        float* dst = &hL1acc[(size_t)row * 96 + h * 24 + c * 8];
#pragma unroll
        for (int d = 0; d < 8; d++) atomicAdd(dst + d, ac * hcv[d]);
    }
}

// ---------- h2 = elu(hL1acc) @ w2  [3072,96]x[96,8] ----------
__global__ __launch_bounds__(256) void k_gemm2(const float* __restrict__ hL1acc,
                                               const float* __restrict__ w2,
                                               float* __restrict__ h2) {
    int id = blockIdx.x * 256 + threadIdx.x;   // 96*256 = 24576 = 3072*8
    int n = id >> 3, j = id & 7;
    float acc = 0.f;
#pragma unroll 8
    for (int k = 0; k < 96; k++) acc += eluf(hL1acc[(size_t)n * 96 + k]) * w2[k * 8 + j];
    h2[n * 8 + j] = acc;
}

// ---------- EGAT2 pass A ----------
__global__ __launch_bounds__(256) void k_e2a(const int* __restrict__ ei,
                                             const float* __restrict__ a2,
                                             const float* __restrict__ h2,
                                             float* __restrict__ ex2,
                                             float* __restrict__ denom2) {
    __shared__ float a2s[16];
    if (threadIdx.x < 16) a2s[threadIdx.x] = a2[threadIdx.x];
    __syncthreads();
    int e = blockIdx.x * 256 + threadIdx.x;
    if (e >= EP) return;
    int row = (e < E_IN) ? ei[e] : (e - E_IN);
    int col = (e < E_IN) ? ei[E_IN + e] : (e - E_IN);
    const float4* H = (const float4*)h2;
    float4 r0 = H[row * 2], r1 = H[row * 2 + 1];
    float4 c0 = H[col * 2], c1 = H[col * 2 + 1];
    float t = r0.x*a2s[0]+r0.y*a2s[1]+r0.z*a2s[2]+r0.w*a2s[3]
            + r1.x*a2s[4]+r1.y*a2s[5]+r1.z*a2s[6]+r1.w*a2s[7]
            + c0.x*a2s[8]+c0.y*a2s[9]+c0.z*a2s[10]+c0.w*a2s[11]
            + c1.x*a2s[12]+c1.y*a2s[13]+c1.z*a2s[14]+c1.w*a2s[15];
    t = t > 0.f ? t : 0.2f * t;
    float ex = expf(t);
    ex2[e] = ex;
    atomicAdd(&denom2[row], ex);
}

// ---------- EGAT2 pass B: thread per (edge, c) ----------
__global__ __launch_bounds__(256) void k_e2b(const int* __restrict__ ei,
                                             const float* __restrict__ e1,
                                             const float* __restrict__ h2,
                                             const float* __restrict__ ex2,
                                             const float* __restrict__ denom2,
                                             float* __restrict__ hL2acc) {
    int id = blockIdx.x * 256 + threadIdx.x;   // 12*EP
    if (id >= 12 * EP) return;
    int e = id / 12, c = id % 12;
    int row = (e < E_IN) ? ei[e] : (e - E_IN);
    int col = (e < E_IN) ? ei[E_IN + e] : (e - E_IN);
    float w = (ex2[e] / (denom2[row] + 1e-16f)) * e1[(size_t)e * 12 + c];
    const float4* H = (const float4*)h2;
    float4 c0 = H[col * 2], c1 = H[col * 2 + 1];
    float hcv[8] = {c0.x,c0.y,c0.z,c0.w,c1.x,c1.y,c1.z,c1.w};
    float* dst = &hL2acc[(size_t)row * 96 + c * 8];
#pragma unroll
    for (int d = 0; d < 8; d++) atomicAdd(dst + d, w * hcv[d]);
}

// ---------- adj pass: t[c,i,m] += s[n,i]*adj[c,n,m] and sum(adj^2) ----------
// grid (3 m-tiles, 12 channels, 24 n-chunks), 256 threads, float4 per lane
__global__ __launch_bounds__(256) void k_adj(const float* __restrict__ adj,
                                             const float* __restrict__ s_soft,
                                             float* __restrict__ tmat,
                                             float* __restrict__ scal) {
    __shared__ float4 snL[128 * 4];   // 128 rows x 16 floats
    __shared__ float wsum[4];
    int tid = threadIdx.x;
    int c  = blockIdx.y;
    int nb = blockIdx.z * 128;
    int m  = blockIdx.x * 1024 + tid * 4;
    const float4* S4 = (const float4*)s_soft;
    for (int l = tid; l < 512; l += 256) snL[l] = S4[(size_t)nb * 4 + l];
    __syncthreads();
    float4 t[16];
#pragma unroll
    for (int i = 0; i < 16; i++) t[i] = make_float4(0.f, 0.f, 0.f, 0.f);
    float sq = 0.f;
    const float* A = adj + (size_t)c * NNsq + (size_t)nb * Nn + m;
#pragma unroll 2
    for (int nn = 0; nn < 128; nn++) {
        float4 a = *(const float4*)(A + (size_t)nn * Nn);
        sq = fmaf(a.x, a.x, sq); sq = fmaf(a.y, a.y, sq);
        sq = fmaf(a.z, a.z, sq); sq = fmaf(a.w, a.w, sq);
#pragma unroll
        for (int k = 0; k < 4; k++) {
            float4 s4 = snL[nn * 4 + k];
            t[k*4+0].x = fmaf(s4.x, a.x, t[k*4+0].x); t[k*4+0].y = fmaf(s4.x, a.y, t[k*4+0].y);
            t[k*4+0].z = fmaf(s4.x, a.z, t[k*4+0].z); t[k*4+0].w = fmaf(s4.x, a.w, t[k*4+0].w);
            t[k*4+1].x = fmaf(s4.y, a.x, t[k*4+1].x); t[k*4+1].y = fmaf(s4.y, a.y, t[k*4+1].y);
            t[k*4+1].z = fmaf(s4.y, a.z, t[k*4+1].z); t[k*4+1].w = fmaf(s4.y, a.w, t[k*4+1].w);
            t[k*4+2].x = fmaf(s4.z, a.x, t[k*4+2].x); t[k*4+2].y = fmaf(s4.z, a.y, t[k*4+2].y);
            t[k*4+2].z = fmaf(s4.z, a.z, t[k*4+2].z); t[k*4+2].w = fmaf(s4.z, a.w, t[k*4+2].w);
            t[k*4+3].x = fmaf(s4.w, a.x, t[k*4+3].x); t[k*4+3].y = fmaf(s4.w, a.y, t[k*4+3].y);
            t[k*4+3].z = fmaf(s4.w, a.z, t[k*4+3].z); t[k*4+3].w = fmaf(s4.w, a.w, t[k*4+3].w);
        }
    }
#pragma unroll
    for (int i = 0; i < 16; i++) {
        float* dst = &tmat[((size_t)c * 16 + i) * 3072 + m];
        atomicAdd(dst + 0, t[i].x); atomicAdd(dst + 1, t[i].y);
        atomicAdd(dst + 2, t[i].z); atomicAdd(dst + 3, t[i].w);
    }
    for (int off = 32; off; off >>= 1) sq += __shfl_xor(sq, off);
    if ((tid & 63) == 0) wsum[tid >> 6] = sq;
    __syncthreads();
    if (tid == 0) atomicAdd(&scal[0], wsum[0] + wsum[1] + wsum[2] + wsum[3]);
}

// ---------- Gram term: scal[3] += 12 * ||S^T S||_F^2 ----------
__global__ __launch_bounds__(256) void k_gram(const float* __restrict__ s_soft,
                                              float* __restrict__ scal) {
    int i = blockIdx.x;   // 16
    int tid = threadIdx.x;
    float acc[16];
#pragma unroll
    for (int j = 0; j < 16; j++) acc[j] = 0.f;
    for (int n = tid; n < 3072; n += 256) {
        float si = s_soft[n * 16 + i];
#pragma unroll
        for (int j = 0; j < 16; j++) acc[j] += si * s_soft[n * 16 + j];
    }
    __shared__ float wpart[16][4];
#pragma unroll
    for (int j = 0; j < 16; j++) {
        float v = acc[j];
        for (int off = 32; off; off >>= 1) v += __shfl_xor(v, off);
        if ((tid & 63) == 0) wpart[j][tid >> 6] = v;
    }
    __syncthreads();
    if (tid < 16) {
        float g = wpart[tid][0] + wpart[tid][1] + wpart[tid][2] + wpart[tid][3];
        atomicAdd(&scal[3], 12.0f * g * g);
    }
}

// ---------- adj1 row + link2 + trace(adj1) ----------
__global__ __launch_bounds__(256) void k_adj2(const float* __restrict__ tmat,
                                              const float* __restrict__ s_soft,
                                              float* __restrict__ scal) {
    int b = blockIdx.x;   // 192 = 12*16  -> (c,i)
    int tid = threadIdx.x;
    const float* trow = tmat + (size_t)b * 3072;
    float acc[16];
#pragma unroll
    for (int j = 0; j < 16; j++) acc[j] = 0.f;
    for (int m = tid; m < 3072; m += 256) {
        float tv = trow[m];
#pragma unroll
        for (int j = 0; j < 16; j++) acc[j] += tv * s_soft[m * 16 + j];
    }
    __shared__ float wpart[16][4];
#pragma unroll
    for (int j = 0; j < 16; j++) {
        float v = acc[j];
        for (int off = 32; off; off >>= 1) v += __shfl_xor(v, off);
        if ((tid & 63) == 0) wpart[j][tid >> 6] = v;
    }
    __syncthreads();
    if (tid < 16) {
        float v = wpart[tid][0] + wpart[tid][1] + wpart[tid][2] + wpart[tid][3];
        float d = v - 1.0f;
        atomicAdd(&scal[1], d * d);
        if (tid == (b & 15)) atomicAdd(&scal[4], v);   // trace(adj1)
    }
}

// ---------- column sum of elu(hL2acc) ----------
__global__ __launch_bounds__(256) void k_colsum(const float* __restrict__ hL2acc,
                                                float* __restrict__ xfin) {
    int f = blockIdx.x;   // 96
    int tid = threadIdx.x;
    float s = 0.f;
    for (int n = tid; n < 3072; n += 256) s += eluf(hL2acc[(size_t)n * 96 + f]);
    __shared__ float wsum[4];
    for (int off = 32; off; off >>= 1) s += __shfl_xor(s, off);
    if ((tid & 63) == 0) wsum[tid >> 6] = s;
    __syncthreads();
    if (tid == 0) xfin[f] = wsum[0] + wsum[1] + wsum[2] + wsum[3];
}

// ---------- FC head + log_softmax + regs ----------
__global__ void k_fc(const float* __restrict__ xfin,
                     const float* __restrict__ w1, const float* __restrict__ b1,
                     const float* __restrict__ w2, const float* __restrict__ b2,
                     const float* __restrict__ w3, const float* __restrict__ b3,
                     const float* __restrict__ w4, const float* __restrict__ b4,
                     const float* __restrict__ scal, float* __restrict__ out) {
    __shared__ float xf[96], z1[128], z2[32], z3[16], z4[2];
    int t = threadIdx.x;  // 128 threads
    if (t < 96) xf[t] = xfin[t];
    __syncthreads();
    {
        float a = b1[t];
        for (int k = 0; k < 96; k++) a += xf[k] * w1[k * 128 + t];
        z1[t] = eluf(a);
    }
    __syncthreads();
    if (t < 32) {
        float a = b2[t];
        for (int k = 0; k < 128; k++) a += z1[k] * w2[k * 32 + t];
        z2[t] = eluf(a);
    }
    __syncthreads();
    if (t < 16) {
        float a = b3[t];
        for (int k = 0; k < 32; k++) a += z2[k] * w3[k * 16 + t];
        z3[t] = eluf(a);
    }
    __syncthreads();
    if (t < 2) {
        float a = b4[t];
        for (int k = 0; k < 16; k++) a += z3[k] * w4[k * 2 + t];
        z4[t] = a;
    }
    __syncthreads();
    if (t == 0) {
        float mx = fmaxf(z4[0], z4[1]);
        float lse = mx + logf(expf(z4[0] - mx) + expf(z4[1] - mx));
        out[0] = z4[0] - lse;
        out[1] = z4[1] - lse;
        float ent1 = -scal[2] / 3072.0f;
        // ||adj - s s^T||_F^2 = sum(adj^2) - 2*trace(adj1) + 12*||S^T S||_F^2
        float l1sq = scal[0] - 2.0f * scal[4] + scal[3];
        float link1 = sqrtf(fmaxf(l1sq, 0.f)) / 113246208.0f;   // adj.size
        out[2] = link1 + ent1;
        float link2 = sqrtf(scal[1]) / 3072.0f;                 // ent2 = -log(1+1e-15) ~ 0
        out[3] = link2;
    }
}

extern "C" void kernel_launch(void* const* d_in, const int* in_sizes, int n_in,
                              void* d_out, int out_size, void* d_ws, size_t ws_size,
                              hipStream_t stream) {
    const float* x    = (const float*)d_in[0];
    const int*   ei   = (const int*)d_in[1];
    const float* ea   = (const float*)d_in[2];
    const float* adj  = (const float*)d_in[3];
    const float* w1   = (const float*)d_in[4];
    const float* a1   = (const float*)d_in[5];
    const float* w2   = (const float*)d_in[6];
    const float* a2   = (const float*)d_in[7];
    const float* s1   = (const float*)d_in[8];
    // d_in[9] = s2: softmax over axis of size 1 == 1.0, unused
    const float* fc1w = (const float*)d_in[10];
    const float* fc1b = (const float*)d_in[11];
    const float* fc2w = (const float*)d_in[12];
    const float* fc2b = (const float*)d_in[13];
    const float* fc3w = (const float*)d_in[14];
    const float* fc3b = (const float*)d_in[15];
    const float* fc4w = (const float*)d_in[16];
    const float* fc4b = (const float*)d_in[17];
    float* out = (float*)d_out;

    float* ws      = (float*)d_ws;
    // zeroed region (contiguous)
    float* tmat    = ws;                       // 589824
    float* hL1acc  = tmat + 589824;            // 294912
    float* hL2acc  = hL1acc + 294912;          // 294912
    float* denom1  = hL2acc + 294912;          // 12288
    float* denom2  = denom1 + 12288;           // 3072
    float* xfin    = denom2 + 3072;            // 96
    float* scal    = xfin + 96;                // 8: [adj2sum, link2sq, entsum, sumP2, trace]
    const size_t ZN = 589824 + 294912 + 294912 + 12288 + 3072 + 96 + 8;
    // non-zeroed region
    float* s_soft  = scal + 8;                 // 49152
    float* h1      = s_soft + 49152;           // 98304
    float* h2      = h1 + 98304;               // 24576
    float* ex1     = h2 + 24576;               // 405504
    float* ex2     = ex1 + 405504;             // 101376
    float* e1      = ex2 + 101376;             // 1216512

    hipMemsetAsync(tmat, 0, ZN * sizeof(float), stream);

    k_softmax<<<12, 256, 0, stream>>>(s1, s_soft, scal);
    k_gemm1<<<384, 256, 0, stream>>>(x, w1, h1);
    k_e1a<<<(EP + 255) / 256, 256, 0, stream>>>(ei, a1, h1, ex1, denom1);
    k_e1b<<<(4 * EP + 255) / 256, 256, 0, stream>>>(ei, ea, h1, ex1, denom1, e1, hL1acc);
    k_gemm2<<<96, 256, 0, stream>>>(hL1acc, w2, h2);
    k_e2a<<<(EP + 255) / 256, 256, 0, stream>>>(ei, a2, h2, ex2, denom2);
    k_e2b<<<(12 * EP + 255) / 256, 256, 0, stream>>>(ei, e1, h2, ex2, denom2, hL2acc);
    k_adj<<<dim3(3, 12, 24), 256, 0, stream>>>(adj, s_soft, tmat, scal);
    k_gram<<<16, 256, 0, stream>>>(s_soft, scal);
    k_adj2<<<192, 256, 0, stream>>>(tmat, s_soft, scal);
    k_colsum<<<96, 256, 0, stream>>>(hL2acc, xfin);
    k_fc<<<1, 128, 0, stream>>>(xfin, fc1w, fc1b, fc2w, fc2b, fc3w, fc3b, fc4w, fc4b, scal, out);
}